// Round 4
// baseline (404.429 us; speedup 1.0000x reference)
//
#include <hip/hip_runtime.h>
#include <math.h>
#include <stdint.h>

// GakeModel: per-node masked-context log-softmax scoring.
// R3 -> R4:
//  - one block per (context, node): grid = 3B, ctx-major.  3x shorter serial
//    chain per block; results combined via atomicAdd into zeroed d_out.
//  - rows stay in REGISTERS (float4 stash per lane), no LDS tile, no bf16:
//    scores via half-wave shfl_xor reduction.  LDS ~2 KB.
//  - sum_s = (S.S)*invn and s0 = (si.S)*invn computed directly; per-row
//    scores only feed an online (m,l) logsumexp.

constexpr int E_ = 500000;  // entity rows
constexpr int R_ = 1000;    // relation rows
constexpr int D_ = 128;     // embedding dim

struct Smem {
  alignas(16) float si[D_];      // si embedding
  alignas(16) float Sp[2][D_];   // per-wave partial row-sums
  float red[8];                  // [0..1] sq, [2..3] m_w, [4..5] l_w
  int cmeta[64];                 // compacted merged row ids (>=E_ -> rel)
  int Vsh;                       // valid-row count
};

__device__ __forceinline__ float bsum(float v) {  // butterfly: all lanes get sum
#pragma unroll
  for (int off = 1; off < 64; off <<= 1) v += __shfl_xor(v, off, 64);
  return v;
}

// Context term.  ACC=true: sum of valid log-p (valid on all threads).
// ACC=false: log-p of row 0 (si).
template <int K, bool ACC>
__device__ float ctx_term(Smem& sm, float si_d,
                          const float* __restrict__ ent,
                          const float* __restrict__ rel,
                          const int* __restrict__ ids,
                          const int* __restrict__ isrel,
                          const int* __restrict__ mask) {
  const int d = threadIdx.x;   // 0..127
  const int w = d >> 6;        // wave id
  const int lane = d & 63;
  const int g = lane >> 5;     // row slot within a wave-instruction (0/1)
  const int cq = lane & 31;    // dim quad: dims 4cq..4cq+3
  constexpr int MAXIT = (K / 2 + 1) / 2;  // 64->16, 16->4

  // --- compaction scan (wave 0) ------------------------------------------
  if (w == 0) {
    int m = 0, midx = 0;
    if (lane < K) {
      m = mask[lane];
      const int id = ids[lane];
      midx = isrel[lane] ? E_ + (id % R_) : id;
    }
    const unsigned long long bal = __ballot(m != 0);
    if (m) sm.cmeta[__popcll(bal & ((1ull << lane) - 1ull))] = midx;
    if (lane == 0) sm.Vsh = (int)__popcll(bal);
  }
  __syncthreads();  // (1) si, cmeta, V published
  const int V = sm.Vsh;
  const int half = (V + 1) >> 1;
  const int rs = w * half;
  const int re = min(V, rs + half);

  // --- gather: wave w loads rows [rs,re), 2 rows (1 KB) per instruction ---
  float4 stash[MAXIT];
#pragma unroll
  for (int it = 0; it < MAXIT; ++it) {
    const int r = rs + 2 * it + g;
    if (rs + 2 * it >= re) break;      // uniform per wave
    int midx = 0;
    if (r < re) midx = sm.cmeta[r];    // off-half clamps to hot ent row 0
    const float* base = (midx >= E_) ? rel + (size_t)(midx - E_) * D_
                                     : ent + (size_t)midx * D_;
    float4 v = *(const float4*)(base + 4 * cq);
    if (r >= re) { v.x = 0.f; v.y = 0.f; v.z = 0.f; v.w = 0.f; }
    stash[it] = v;
  }

  // --- fold: masked row-sum partial (per quad) + sq-norm ------------------
  float4 Sp = make_float4(0.f, 0.f, 0.f, 0.f);
  float sq = si_d * si_d;  // thread's own dim of si
#pragma unroll
  for (int it = 0; it < MAXIT; ++it) {
    if (rs + 2 * it >= re) break;
    const float4 v = stash[it];
    Sp.x += v.x; Sp.y += v.y; Sp.z += v.z; Sp.w += v.w;
    sq += v.x * v.x + v.y * v.y + v.z * v.z + v.w * v.w;
  }
  Sp.x += __shfl_xor(Sp.x, 32, 64);
  Sp.y += __shfl_xor(Sp.y, 32, 64);
  Sp.z += __shfl_xor(Sp.z, 32, 64);
  Sp.w += __shfl_xor(Sp.w, 32, 64);
  if (lane < 32) *(float4*)&sm.Sp[w][4 * cq] = Sp;
  const float wq = bsum(sq);
  if (lane == 0) sm.red[w] = wq;
  __syncthreads();  // (2) Sp partials + sq published

  // --- S quad, norm, direct sums -----------------------------------------
  const float4 si4 = *(const float4*)&sm.si[4 * cq];
  const float4 a0 = *(const float4*)&sm.Sp[0][4 * cq];
  const float4 a1 = *(const float4*)&sm.Sp[1][4 * cq];
  float4 S4;
  S4.x = si4.x + a0.x + a1.x;
  S4.y = si4.y + a0.y + a1.y;
  S4.z = si4.z + a0.z + a1.z;
  S4.w = si4.w + a0.w + a1.w;
  const float invn = rsqrtf(sm.red[0] + sm.red[1]);

  // Each quad appears twice per wave (lanes l, l^32) -> x0.5 after bsum.
  const float t1 = S4.x * S4.x + S4.y * S4.y + S4.z * S4.z + S4.w * S4.w;
  const float t2 = si4.x * S4.x + si4.y * S4.y + si4.z * S4.z + si4.w * S4.w;
  const float sum_s = bsum(t1) * 0.5f * invn;  // = sum over ALL valid rows
  const float s0 = bsum(t2) * 0.5f * invn;     // = si score (row 0)

  // --- per-row scores -> online (m,l) logsumexp ---------------------------
  float m = -INFINITY, l = 0.f;
#pragma unroll
  for (int it = 0; it < MAXIT; ++it) {
    if (rs + 2 * it >= re) break;
    const int r = rs + 2 * it + g;
    const float4 v = stash[it];
    float p = v.x * S4.x + v.y * S4.y + v.z * S4.z + v.w * S4.w;
#pragma unroll
    for (int off = 1; off < 32; off <<= 1) p += __shfl_xor(p, off, 64);
    if (r < re) {  // uniform per 32-half
      const float s = p * invn;
      const float mn = fmaxf(m, s);
      l = l * __expf(m - mn) + __expf(s - mn);
      m = mn;
    }
  }
  // merge the two 32-halves of this wave
  const float m2 = __shfl_xor(m, 32, 64);
  const float l2 = __shfl_xor(l, 32, 64);
  const float mw = fmaxf(m, m2);
  const float lw = (mw == -INFINITY)
                       ? 0.f
                       : l * __expf(m - mw) + l2 * __expf(m2 - mw);
  if (lane == 0) { sm.red[2 + w] = mw; sm.red[4 + w] = lw; }
  __syncthreads();  // (3) wave (m,l) published

  // final merge: wave0, wave1, and s0 (mfin finite since s0 finite)
  const float m0 = sm.red[2], m1 = sm.red[3];
  const float l0 = sm.red[4], l1 = sm.red[5];
  const float mfin = fmaxf(fmaxf(m0, m1), s0);
  const float lfin = l0 * __expf(m0 - mfin) + l1 * __expf(m1 - mfin) +
                     __expf(s0 - mfin);
  const float logZ = __logf(lfin);

  if (ACC) return sum_s - (float)(V + 1) * (mfin + logZ);
  return s0 - mfin - logZ;
}

__global__ __launch_bounds__(128, 4) void gake_kernel(
    const float* __restrict__ ent, const float* __restrict__ rel,
    const int* __restrict__ node_ids, const int* __restrict__ node_isrel,
    const int* __restrict__ nbr_ids, const int* __restrict__ nbr_isrel,
    const int* __restrict__ nbr_mask, const int* __restrict__ path_ids,
    const int* __restrict__ path_isrel, const int* __restrict__ path_mask,
    const int* __restrict__ edge_ids, const int* __restrict__ edge_isrel,
    const int* __restrict__ edge_mask, float* __restrict__ out, int B) {
  __shared__ Smem sm;
  const int bid = blockIdx.x;
  const int ctx = bid / B;      // 0=nbr, 1=path, 2=edge (ctx-major grid)
  const int b = bid - ctx * B;
  const int d = threadIdx.x;

  const int nid = node_ids[b];
  const float* srow = node_isrel[b] ? rel + (size_t)(nid % R_) * D_
                                    : ent + (size_t)nid * D_;
  const float si_d = srow[d];
  sm.si[d] = si_d;  // published by barrier (1) inside ctx_term

  float term, wgt;
  if (ctx == 0) {
    term = ctx_term<64, true>(sm, si_d, ent, rel, nbr_ids + (size_t)b * 64,
                              nbr_isrel + (size_t)b * 64,
                              nbr_mask + (size_t)b * 64);
    wgt = 1.0f;
  } else if (ctx == 1) {
    term = ctx_term<64, true>(sm, si_d, ent, rel, path_ids + (size_t)b * 64,
                              path_isrel + (size_t)b * 64,
                              path_mask + (size_t)b * 64);
    wgt = 0.1f;
  } else {
    term = ctx_term<16, false>(sm, si_d, ent, rel, edge_ids + (size_t)b * 16,
                               edge_isrel + (size_t)b * 16,
                               edge_mask + (size_t)b * 16);
    wgt = 0.1f;
  }
  if (d == 0) atomicAdd(out + b, -wgt * term);
}

extern "C" void kernel_launch(void* const* d_in, const int* in_sizes, int n_in,
                              void* d_out, int out_size, void* d_ws,
                              size_t ws_size, hipStream_t stream) {
  const float* ent = (const float*)d_in[0];
  const float* rel = (const float*)d_in[1];
  const int* node_ids = (const int*)d_in[2];
  const int* node_isrel = (const int*)d_in[3];
  const int* nbr_ids = (const int*)d_in[4];
  const int* nbr_isrel = (const int*)d_in[5];
  const int* nbr_mask = (const int*)d_in[6];
  const int* path_ids = (const int*)d_in[7];
  const int* path_isrel = (const int*)d_in[8];
  const int* path_mask = (const int*)d_in[9];
  const int* edge_ids = (const int*)d_in[10];
  const int* edge_isrel = (const int*)d_in[11];
  const int* edge_mask = (const int*)d_in[12];
  float* out = (float*)d_out;

  const int B = in_sizes[2];  // node_ids element count = batch
  // out is poisoned 0xAA before every timed launch; we accumulate into it.
  hipMemsetAsync(d_out, 0, (size_t)out_size * sizeof(float), stream);
  gake_kernel<<<3 * B, 128, 0, stream>>>(
      ent, rel, node_ids, node_isrel, nbr_ids, nbr_isrel, nbr_mask, path_ids,
      path_isrel, path_mask, edge_ids, edge_isrel, edge_mask, out, B);
}